// Round 3
// baseline (412.307 us; speedup 1.0000x reference)
//
#include <hip/hip_runtime.h>

#define BB 32
#define NN 4096
#define DD 256
#define HH 4
#define KK 8
#define DH 64

typedef unsigned short u16;
typedef unsigned int u32;
typedef __attribute__((ext_vector_type(8))) short short8;
typedef __attribute__((ext_vector_type(4))) float f32x4;

__device__ __forceinline__ float b2f(u16 u){ return __uint_as_float(((u32)u)<<16); }
__device__ __forceinline__ u16 f2b(float f){
  u32 u = __float_as_uint(f);
  u32 r = (u + 0x7fffu + ((u>>16)&1u)) >> 16;  // RNE
  return (u16)r;
}

// ---------------- prep: convert weights to bf16, init slots ----------------
__global__ __launch_bounds__(256) void prep_kernel(
    const float* __restrict__ mu, const float* __restrict__ w_q,
    const float* __restrict__ w_k, const float* __restrict__ w_v,
    const float* __restrict__ w_comb, const float* __restrict__ w_ih,
    const float* __restrict__ w_hh, const float* __restrict__ w1,
    const float* __restrict__ w2,
    u16* __restrict__ wkv, u16* __restrict__ wq_b, u16* __restrict__ wcomb_b,
    u16* __restrict__ wih_b, u16* __restrict__ whh_b, u16* __restrict__ w1_b,
    u16* __restrict__ w2_b, float* __restrict__ slots)
{
  int i = blockIdx.x*256 + threadIdx.x;
  if (i < 131072) {          // wkv: [512 cols][256 k] plain row-major (K rows then V rows)
    wkv[i] = f2b((i < 65536) ? w_k[i] : w_v[i-65536]);
    return;
  }
  i -= 131072;
  if (i < 65536){ wq_b[i] = f2b(w_q[i]); return; } i -= 65536;
  if (i < 65536){ wcomb_b[i] = f2b(w_comb[i]); return; } i -= 65536;
  if (i < 196608){ wih_b[i] = f2b(w_ih[i]); return; } i -= 196608;
  if (i < 196608){ whh_b[i] = f2b(w_hh[i]); return; } i -= 196608;
  if (i < 65536){ w1_b[i] = f2b(w1[i]); return; } i -= 65536;
  if (i < 65536){ w2_b[i] = f2b(w2[i]); return; } i -= 65536;
  if (i < 65536){ slots[i] = mu[i & 2047]; return; }
}

// ---------------- phase A: fused LN(x) + K/V projection (MFMA bf16) ----------------
// 64 rows x 512 cols per block, 8 waves. A-frags register-resident; B direct from
// global (L2-hot weights); Cbuf ping-pong -> 1 barrier/chunk, stores overlap MFMA.
__global__ __launch_bounds__(512,4) void kv_proj_kernel(
    const float* __restrict__ x, const float* __restrict__ g_in,
    const float* __restrict__ b_in, const u16* __restrict__ wkv,
    u16* __restrict__ Kmat, u16* __restrict__ Vmat)
{
  __shared__ __align__(16) u16 Atile[64*256];   // 32 KB, swizzled [row][k]
  __shared__ __align__(16) u16 Cbuf[2][64*64];  // 2 x 8 KB ping-pong
  const int tid = threadIdx.x;
  const int w = tid>>6, l = tid&63;
  const long row0 = (long)blockIdx.x * 64;
  const int wm = w>>2, wn = w&3;
  const int lr = l&15, lk = (l>>4)*8;

  // B chunk-0 loads (L2-resident weights), issued first
  const u16* bp = wkv + (wn*16 + lr)*256 + lk;
  short8 bf[8];
  #pragma unroll
  for (int ks=0;ks<8;++ks) bf[ks] = *(const short8*)(bp + ks*32);

  // x rows up-front for load ILP
  f32x4 xr[8];
  #pragma unroll
  for (int rr=0;rr<8;++rr)
    xr[rr] = *(const f32x4*)(x + (row0 + w*8 + rr)*DD + l*4);

  const f32x4 gv = *(const f32x4*)(g_in + l*4);
  const f32x4 bv = *(const f32x4*)(b_in + l*4);

  #pragma unroll
  for (int rr=0; rr<8; ++rr) {
    const int r = w*8 + rr;
    const f32x4 xv = xr[rr];
    float s = xv.x+xv.y+xv.z+xv.w;
    float s2 = xv.x*xv.x+xv.y*xv.y+xv.z*xv.z+xv.w*xv.w;
    #pragma unroll
    for (int m=1;m<64;m<<=1){ s += __shfl_xor(s,m); s2 += __shfl_xor(s2,m); }
    const float mean = s * (1.f/256.f);
    const float rstd = rsqrtf(s2*(1.f/256.f) - mean*mean + 1e-5f);
    const u32 p0 = (u32)f2b((xv.x-mean)*rstd*gv.x + bv.x) | ((u32)f2b((xv.y-mean)*rstd*gv.y + bv.y)<<16);
    const u32 p1 = (u32)f2b((xv.z-mean)*rstd*gv.z + bv.z) | ((u32)f2b((xv.w-mean)*rstd*gv.w + bv.w)<<16);
    const unsigned long long pp = (unsigned long long)p0 | ((unsigned long long)p1<<32);
    *(unsigned long long*)((char*)Atile + r*512 + ((l*8) ^ ((r&15)<<4))) = pp;
  }
  __syncthreads();

  // A-fragments register-resident (read LDS once)
  short8 afr0[8], afr1[8];
  #pragma unroll
  for (int ks=0;ks<8;++ks) {
    const int k2 = (ks*32 + lk)*2;
    { const int r = wm*32 + lr;      afr0[ks] = *(const short8*)((const char*)Atile + r*512 + (k2 ^ ((r&15)<<4))); }
    { const int r = wm*32 + 16 + lr; afr1[ks] = *(const short8*)((const char*)Atile + r*512 + (k2 ^ ((r&15)<<4))); }
  }

  #pragma unroll
  for (int ct=0; ct<8; ++ct) {   // ct 0..3 -> K cols ct*64 ; 4..7 -> V cols (ct-4)*64
    // readback previous chunk's C (overlaps this chunk's pure-compute MFMA phase)
    if (ct > 0) {
      const int r = tid>>3, cg = tid&7;
      const short8 vv = *(const short8*)((char*)Cbuf[(ct-1)&1] + r*128 + ((cg*16) ^ ((r&7)<<4)));
      u16* dst = ((ct-1)<4) ? Kmat : Vmat;
      *(short8*)(dst + (row0+r)*DD + ((ct-1)&3)*64 + cg*8) = vv;
    }

    f32x4 acc0 = (f32x4)0.f, acc1 = (f32x4)0.f;
    #pragma unroll
    for (int ks=0;ks<8;++ks) {
      acc0 = __builtin_amdgcn_mfma_f32_16x16x32_bf16(afr0[ks], bf[ks], acc0, 0,0,0);
      acc1 = __builtin_amdgcn_mfma_f32_16x16x32_bf16(afr1[ks], bf[ks], acc1, 0,0,0);
    }

    // issue next chunk's B loads (complete across the barrier drain)
    if (ct < 7) {
      #pragma unroll
      for (int ks=0;ks<8;++ks) bf[ks] = *(const short8*)(bp + (ct+1)*16384 + ks*32);
    }

    // write C frags (bf16, swizzled) into Cbuf[ct&1]
    {
      const int c = wn*16 + lr;
      #pragma unroll
      for (int reg=0; reg<4; ++reg) {
        const int r0r = wm*32 + (l>>4)*4 + reg;
        const int r1r = r0r + 16;
        *(u16*)((char*)Cbuf[ct&1] + r0r*128 + ((2*c) ^ ((r0r&7)<<4))) = f2b(acc0[reg]);
        *(u16*)((char*)Cbuf[ct&1] + r1r*128 + ((2*c) ^ ((r1r&7)<<4))) = f2b(acc1[reg]);
      }
    }
    __syncthreads();
  }
  // epilogue: readback chunk 7
  {
    const int r = tid>>3, cg = tid&7;
    const short8 vv = *(const short8*)((char*)Cbuf[1] + r*128 + ((cg*16) ^ ((r&7)<<4)));
    *(short8*)(Vmat + (row0+r)*DD + 3*64 + cg*8) = vv;
  }
}

// ---------------- iter-1 only: q = split(LN(slots) @ w_q^T) ----------------
__global__ __launch_bounds__(256) void slot_q_kernel(
    const float* __restrict__ slots, const float* __restrict__ g_slot,
    const float* __restrict__ b_slot, const u16* __restrict__ wq_b,
    float* __restrict__ qmat)
{
  __shared__ float xn[256];
  __shared__ float red[8];
  const int r = blockIdx.x, t = threadIdx.x;
  const int w = t>>6, l = t&63;
  const float xv = slots[r*256 + t];
  float s = xv, s2 = xv*xv;
  #pragma unroll
  for (int m=1;m<64;m<<=1){ s += __shfl_xor(s,m); s2 += __shfl_xor(s2,m); }
  if (l==0){ red[w*2]=s; red[w*2+1]=s2; }
  __syncthreads();
  s = red[0]+red[2]+red[4]+red[6];
  s2 = red[1]+red[3]+red[5]+red[7];
  const float mean = s*(1.f/256.f);
  const float rstd = rsqrtf(s2*(1.f/256.f)-mean*mean + 1e-5f);
  xn[t] = (xv-mean)*rstd*g_slot[t] + b_slot[t];
  __syncthreads();
  const u16* wr = wq_b + t*256;
  float a0=0,a1=0,a2=0,a3=0;
  for (int d=0; d<256; d+=8) {
    const short8 wv = *(const short8*)(wr + d);
    a0 = fmaf(b2f((u16)wv[0]), xn[d+0], a0);
    a1 = fmaf(b2f((u16)wv[1]), xn[d+1], a1);
    a2 = fmaf(b2f((u16)wv[2]), xn[d+2], a2);
    a3 = fmaf(b2f((u16)wv[3]), xn[d+3], a3);
    a0 = fmaf(b2f((u16)wv[4]), xn[d+4], a0);
    a1 = fmaf(b2f((u16)wv[5]), xn[d+5], a1);
    a2 = fmaf(b2f((u16)wv[6]), xn[d+6], a2);
    a3 = fmaf(b2f((u16)wv[7]), xn[d+7], a3);
  }
  qmat[r*256 + t] = ((a0+a1)+(a2+a3));
}

// ---------------- per-iter: fused dots -> softmax(k) -> partial sums of p and p*v ----------------
__global__ __launch_bounds__(256) void attn_kernel(
    const u16* __restrict__ Kmat, const u16* __restrict__ Vmat,
    const float* __restrict__ qmat, float* __restrict__ U_part,
    float* __restrict__ S_part)
{
  __shared__ float U_lds[4][8][64];
  __shared__ float S_lds[4][8];
  const int bid = blockIdx.x;
  const int part = bid & 3, h = (bid>>2)&3, b = bid>>4;
  const int t = threadIdx.x, w = t>>6, l = t&63;
  const int ds = l&7, ng = l>>3;   // 8 lanes per n; ds = d-slice

  float qreg[8][8];
  #pragma unroll
  for (int k=0;k<8;++k) {
    const f32x4 qa = *(const f32x4*)(qmat + (b*8+k)*256 + h*64 + ds*8);
    const f32x4 qb = *(const f32x4*)(qmat + (b*8+k)*256 + h*64 + ds*8 + 4);
    qreg[k][0]=qa.x; qreg[k][1]=qa.y; qreg[k][2]=qa.z; qreg[k][3]=qa.w;
    qreg[k][4]=qb.x; qreg[k][5]=qb.y; qreg[k][6]=qb.z; qreg[k][7]=qb.w;
  }

  float accU[8][8];
  float sacc[8];
  #pragma unroll
  for (int k=0;k<8;++k){ sacc[k]=0.f;
    #pragma unroll
    for (int j=0;j<8;++j) accU[k][j]=0.f; }

  const long base = ((long)b*NN)*DD + h*64;
  const u16* Kp = Kmat + base + (long)(part*1024 + w*8 + ng)*DD + ds*8;
  const u16* Vp = Vmat + base + (long)(part*1024 + w*8 + ng)*DD + ds*8;

  short8 kc = *(const short8*)Kp;
  short8 vc = *(const short8*)Vp;
  for (int pass=0; pass<32; ++pass) {
    short8 kn, vn;
    if (pass < 31) {                 // prefetch next pass's K AND V
      kn = *(const short8*)(Kp + (pass+1)*32*DD);
      vn = *(const short8*)(Vp + (pass+1)*32*DD);
    }
    float kd[8];
    #pragma unroll
    for (int j=0;j<8;++j) kd[j] = b2f((u16)kc[j]);
    float dots[8];
    #pragma unroll
    for (int k=0;k<8;++k) {
      float d0 = qreg[k][0]*kd[0] + qreg[k][1]*kd[1] + qreg[k][2]*kd[2] + qreg[k][3]*kd[3]
               + qreg[k][4]*kd[4] + qreg[k][5]*kd[5] + qreg[k][6]*kd[6] + qreg[k][7]*kd[7];
      d0 += __shfl_xor(d0,1); d0 += __shfl_xor(d0,2); d0 += __shfl_xor(d0,4);
      dots[k] = d0 * 0.125f;   // SCALE = d_h^-0.5
    }
    float mx = dots[0];
    #pragma unroll
    for (int k=1;k<8;++k) mx = fmaxf(mx, dots[k]);
    float e[8]; float se = 0.f;
    #pragma unroll
    for (int k=0;k<8;++k){ e[k] = __expf(dots[k]-mx); se += e[k]; }
    const float inv = 1.f/se;
    float vd[8];
    #pragma unroll
    for (int j=0;j<8;++j) vd[j] = b2f((u16)vc[j]);
    #pragma unroll
    for (int k=0;k<8;++k) {
      const float p = e[k]*inv;
      sacc[k] += p;
      #pragma unroll
      for (int j=0;j<8;++j) accU[k][j] = fmaf(p, vd[j], accU[k][j]);
    }
    kc = kn; vc = vn;
  }
  // reduce across the 8 n-groups of the wave (deterministic)
  #pragma unroll
  for (int k=0;k<8;++k){
    #pragma unroll
    for (int j=0;j<8;++j){
      float v = accU[k][j];
      v += __shfl_xor(v,8); v += __shfl_xor(v,16); v += __shfl_xor(v,32);
      accU[k][j]=v;
    }
    float sv = sacc[k];
    sv += __shfl_xor(sv,8); sv += __shfl_xor(sv,16); sv += __shfl_xor(sv,32);
    sacc[k]=sv;
  }
  if (l<8){
    #pragma unroll
    for (int k=0;k<8;++k)
      #pragma unroll
      for (int j=0;j<8;++j) U_lds[w][k][l*8+j] = accU[k][j];
  }
  if (l==0){
    #pragma unroll
    for (int k=0;k<8;++k) S_lds[w][k]=sacc[k];
  }
  __syncthreads();
  for (int i=t;i<512;i+=256){
    const int k=i>>6, d=i&63;
    U_part[(((long)part*32 + b)*4 + h)*512 + k*64 + d] =
      U_lds[0][k][d]+U_lds[1][k][d]+U_lds[2][k][d]+U_lds[3][k][d];
  }
  if (t<8){
    S_part[((part*32 + b)*4 + h)*8 + t] = S_lds[0][t]+S_lds[1][t]+S_lds[2][t]+S_lds[3][t];
  }
}

// ---------------- per-iter: renorm + comb + GRU + MLP (+ fused next-iter q) ----------------
__global__ __launch_bounds__(256) void slot_update_kernel(
    const float* __restrict__ U_part, const float* __restrict__ S_part,
    float* __restrict__ slots,
    const u16* __restrict__ wcomb_b, const u16* __restrict__ wih_b,
    const u16* __restrict__ whh_b, const u16* __restrict__ w1_b,
    const u16* __restrict__ w2_b,
    const float* __restrict__ b_ih, const float* __restrict__ b_hh,
    const float* __restrict__ g_mlp, const float* __restrict__ b_mlp,
    const float* __restrict__ b1v, const float* __restrict__ b2v,
    const u16* __restrict__ wq_b, const float* __restrict__ g_slot,
    const float* __restrict__ b_slot, float* __restrict__ qmat,
    float* __restrict__ out_final, const int write_out, const int compute_q)
{
  __shared__ float uL[2][256];
  __shared__ float hL[2][256];
  __shared__ float cL[2][256];
  __shared__ float xL[2][256];
  __shared__ float red[16];
  const int blk = blockIdx.x, t = threadIdx.x;
  const int w = t>>6, l = t&63;
  const int r0 = blk*2;

  #pragma unroll
  for (int rr=0;rr<2;++rr) hL[rr][t] = slots[(r0+rr)*256 + t];

  #pragma unroll
  for (int rr=0;rr<2;++rr) {
    const int r = r0+rr, b = r>>3, k = r&7;
    const int h = t>>6, d = t&63;
    float ssum = 0.f, usum = 0.f;
    #pragma unroll
    for (int p=0;p<4;++p) {
      ssum += S_part[((p*32 + b)*4 + h)*8 + k];
      usum += U_part[(((long)p*32 + b)*4 + h)*512 + k*64 + d];
    }
    uL[rr][t] = usum / (ssum + 1e-8f);
  }
  __syncthreads();

  {  // comb = upd @ w_comb^T
    float c00=0,c01=0,c10=0,c11=0;
    const u16* wr = wcomb_b + t*256;
    for (int d0=0; d0<256; d0+=8) {
      const short8 wv = *(const short8*)(wr + d0);
      float wf[8];
      #pragma unroll
      for (int j=0;j<8;++j) wf[j]=b2f((u16)wv[j]);
      #pragma unroll
      for (int j=0;j<8;j+=2) {
        c00 = fmaf(wf[j],   uL[0][d0+j],   c00);
        c01 = fmaf(wf[j+1], uL[0][d0+j+1], c01);
        c10 = fmaf(wf[j],   uL[1][d0+j],   c10);
        c11 = fmaf(wf[j+1], uL[1][d0+j+1], c11);
      }
    }
    cL[0][t]=c00+c01; cL[1][t]=c10+c11;
  }
  __syncthreads();

  // GRU gates: gi from cL (u), gh from hL (h)
  float gi[3][2], gh[3][2];
  #pragma unroll
  for (int g=0; g<3; ++g){ gi[g][0]=0; gi[g][1]=0; gh[g][0]=0; gh[g][1]=0; }
  for (int d0=0; d0<256; d0+=8) {
    float u0[8],u1[8],h0[8],h1[8];
    #pragma unroll
    for (int j=0;j<8;j+=4) {
      *(f32x4*)&u0[j] = *(const f32x4*)&cL[0][d0+j];
      *(f32x4*)&u1[j] = *(const f32x4*)&cL[1][d0+j];
      *(f32x4*)&h0[j] = *(const f32x4*)&hL[0][d0+j];
      *(f32x4*)&h1[j] = *(const f32x4*)&hL[1][d0+j];
    }
    #pragma unroll
    for (int g=0; g<3; ++g) {
      const short8 wi = *(const short8*)(wih_b + (g*256+t)*256 + d0);
      const short8 wh = *(const short8*)(whh_b + (g*256+t)*256 + d0);
      #pragma unroll
      for (int j=0;j<8;++j) {
        const float a = b2f((u16)wi[j]);
        const float bw = b2f((u16)wh[j]);
        gi[g][0] = fmaf(a, u0[j], gi[g][0]);
        gi[g][1] = fmaf(a, u1[j], gi[g][1]);
        gh[g][0] = fmaf(bw, h0[j], gh[g][0]);
        gh[g][1] = fmaf(bw, h1[j], gh[g][1]);
      }
    }
  }
  float newv[2];
  #pragma unroll
  for (int rr=0;rr<2;++rr) {
    const float ir = gi[0][rr] + b_ih[t];
    const float iz = gi[1][rr] + b_ih[256+t];
    const float inn= gi[2][rr] + b_ih[512+t];
    const float hr = gh[0][rr] + b_hh[t];
    const float hz = gh[1][rr] + b_hh[256+t];
    const float hn = gh[2][rr] + b_hh[512+t];
    const float rg = 1.f/(1.f + __expf(-(ir+hr)));
    const float zg = 1.f/(1.f + __expf(-(iz+hz)));
    float targ = inn + rg*hn;
    targ = fminf(fmaxf(targ, -15.f), 15.f);
    const float ex = __expf(2.f*targ);
    const float ng = (ex-1.f)/(ex+1.f);
    newv[rr] = (1.f-zg)*ng + zg*hL[rr][t];
  }

  // LN(new) with g_mlp/b_mlp
  float s0=newv[0], q0=newv[0]*newv[0], s1=newv[1], q1=newv[1]*newv[1];
  #pragma unroll
  for (int m=1;m<64;m<<=1){
    s0+=__shfl_xor(s0,m); q0+=__shfl_xor(q0,m);
    s1+=__shfl_xor(s1,m); q1+=__shfl_xor(q1,m);
  }
  if (l==0){ red[w*4]=s0; red[w*4+1]=q0; red[w*4+2]=s1; red[w*4+3]=q1; }
  __syncthreads();
  s0 = red[0]+red[4]+red[8]+red[12];
  q0 = red[1]+red[5]+red[9]+red[13];
  s1 = red[2]+red[6]+red[10]+red[14];
  q1 = red[3]+red[7]+red[11]+red[15];
  {
    const float m0 = s0*(1.f/256.f), m1 = s1*(1.f/256.f);
    const float r0v = rsqrtf(q0*(1.f/256.f)-m0*m0 + 1e-5f);
    const float r1v = rsqrtf(q1*(1.f/256.f)-m1*m1 + 1e-5f);
    xL[0][t] = (newv[0]-m0)*r0v*g_mlp[t] + b_mlp[t];
    xL[1][t] = (newv[1]-m1)*r1v*g_mlp[t] + b_mlp[t];
  }
  __syncthreads();

  {  // hid = relu(xn2 @ w1^T + b1) -> uL (reuse)
    float c00=0,c01=0,c10=0,c11=0;
    const u16* wr = w1_b + t*256;
    for (int d0=0; d0<256; d0+=8) {
      const short8 wv = *(const short8*)(wr + d0);
      float wf[8];
      #pragma unroll
      for (int j=0;j<8;++j) wf[j]=b2f((u16)wv[j]);
      #pragma unroll
      for (int j=0;j<8;j+=2) {
        c00 = fmaf(wf[j],   xL[0][d0+j],   c00);
        c01 = fmaf(wf[j+1], xL[0][d0+j+1], c01);
        c10 = fmaf(wf[j],   xL[1][d0+j],   c10);
        c11 = fmaf(wf[j+1], xL[1][d0+j+1], c11);
      }
    }
    uL[0][t] = fmaxf(c00+c01 + b1v[t], 0.f);
    uL[1][t] = fmaxf(c10+c11 + b1v[t], 0.f);
  }
  __syncthreads();

  float o0, o1;
  {  // out = new + hid @ w2^T + b2
    float c00=0,c01=0,c10=0,c11=0;
    const u16* wr = w2_b + t*256;
    for (int d0=0; d0<256; d0+=8) {
      const short8 wv = *(const short8*)(wr + d0);
      float wf[8];
      #pragma unroll
      for (int j=0;j<8;++j) wf[j]=b2f((u16)wv[j]);
      #pragma unroll
      for (int j=0;j<8;j+=2) {
        c00 = fmaf(wf[j],   uL[0][d0+j],   c00);
        c01 = fmaf(wf[j+1], uL[0][d0+j+1], c01);
        c10 = fmaf(wf[j],   uL[1][d0+j],   c10);
        c11 = fmaf(wf[j+1], uL[1][d0+j+1], c11);
      }
    }
    o0 = newv[0] + c00+c01 + b2v[t];
    o1 = newv[1] + c10+c11 + b2v[t];
    slots[(r0+0)*256 + t] = o0;
    slots[(r0+1)*256 + t] = o1;
    if (write_out){
      out_final[(r0+0)*256 + t] = o0;
      out_final[(r0+1)*256 + t] = o1;
    }
  }

  if (compute_q) {   // fused next-iteration q = split(LN(out) @ w_q^T)
    __syncthreads();
    float t0=o0, p0=o0*o0, t1=o1, p1=o1*o1;
    #pragma unroll
    for (int m=1;m<64;m<<=1){
      t0+=__shfl_xor(t0,m); p0+=__shfl_xor(p0,m);
      t1+=__shfl_xor(t1,m); p1+=__shfl_xor(p1,m);
    }
    if (l==0){ red[w*4]=t0; red[w*4+1]=p0; red[w*4+2]=t1; red[w*4+3]=p1; }
    __syncthreads();
    t0 = red[0]+red[4]+red[8]+red[12];
    p0 = red[1]+red[5]+red[9]+red[13];
    t1 = red[2]+red[6]+red[10]+red[14];
    p1 = red[3]+red[7]+red[11]+red[15];
    const float m0 = t0*(1.f/256.f), m1 = t1*(1.f/256.f);
    const float r0v = rsqrtf(p0*(1.f/256.f)-m0*m0 + 1e-5f);
    const float r1v = rsqrtf(p1*(1.f/256.f)-m1*m1 + 1e-5f);
    cL[0][t] = (o0-m0)*r0v*g_slot[t] + b_slot[t];
    cL[1][t] = (o1-m1)*r1v*g_slot[t] + b_slot[t];
    __syncthreads();
    float c00=0,c01=0,c10=0,c11=0;
    const u16* wr = wq_b + t*256;
    for (int d0=0; d0<256; d0+=8) {
      const short8 wv = *(const short8*)(wr + d0);
      float wf[8];
      #pragma unroll
      for (int j=0;j<8;++j) wf[j]=b2f((u16)wv[j]);
      #pragma unroll
      for (int j=0;j<8;j+=2) {
        c00 = fmaf(wf[j],   cL[0][d0+j],   c00);
        c01 = fmaf(wf[j+1], cL[0][d0+j+1], c01);
        c10 = fmaf(wf[j],   cL[1][d0+j],   c10);
        c11 = fmaf(wf[j+1], cL[1][d0+j+1], c11);
      }
    }
    qmat[(r0+0)*256 + t] = c00+c01;
    qmat[(r0+1)*256 + t] = c10+c11;
  }
}

extern "C" void kernel_launch(void* const* d_in, const int* in_sizes, int n_in,
                              void* d_out, int out_size, void* d_ws, size_t ws_size,
                              hipStream_t stream)
{
  (void)in_sizes; (void)n_in; (void)out_size; (void)ws_size;
  const float* x      = (const float*)d_in[0];
  const float* mu     = (const float*)d_in[1];
  const float* w_q    = (const float*)d_in[2];
  const float* w_k    = (const float*)d_in[3];
  const float* w_v    = (const float*)d_in[4];
  const float* w_comb = (const float*)d_in[5];
  const float* g_in   = (const float*)d_in[6];
  const float* b_in   = (const float*)d_in[7];
  const float* g_slot = (const float*)d_in[8];
  const float* b_slot = (const float*)d_in[9];
  const float* g_mlp  = (const float*)d_in[10];
  const float* b_mlp  = (const float*)d_in[11];
  const float* w_ih   = (const float*)d_in[12];
  const float* w_hh   = (const float*)d_in[13];
  const float* b_ih   = (const float*)d_in[14];
  const float* b_hh   = (const float*)d_in[15];
  const float* w1     = (const float*)d_in[16];
  const float* b1     = (const float*)d_in[17];
  const float* w2     = (const float*)d_in[18];
  const float* b2     = (const float*)d_in[19];

  char* ws = (char*)d_ws;
  u16* Kmat    = (u16*)(ws + 0);
  u16* Vmat    = (u16*)(ws + 67108864);
  u16* wkv     = (u16*)(ws + 134217728);
  u16* wq_b    = (u16*)(ws + 134479872);
  u16* wcomb_b = (u16*)(ws + 134610944);
  u16* wih_b   = (u16*)(ws + 134742016);
  u16* whh_b   = (u16*)(ws + 135135232);
  u16* w1_b    = (u16*)(ws + 135528448);
  u16* w2_b    = (u16*)(ws + 135659520);
  float* slots = (float*)(ws + 135790592);
  float* qmat  = (float*)(ws + 136052736);
  float* U_part= (float*)(ws + 136314880);
  float* S_part= (float*)(ws + 137363456);

  hipLaunchKernelGGL(prep_kernel, dim3(3328), dim3(256), 0, stream,
                     mu, w_q, w_k, w_v, w_comb, w_ih, w_hh, w1, w2,
                     wkv, wq_b, wcomb_b, wih_b, whh_b, w1_b, w2_b, slots);
  hipLaunchKernelGGL(kv_proj_kernel, dim3(2048), dim3(512), 0, stream,
                     x, g_in, b_in, wkv, Kmat, Vmat);
  hipLaunchKernelGGL(slot_q_kernel, dim3(256), dim3(256), 0, stream,
                     slots, g_slot, b_slot, wq_b, qmat);
  float* outp = (float*)d_out;
  for (int it=0; it<3; ++it) {
    hipLaunchKernelGGL(attn_kernel, dim3(512), dim3(256), 0, stream,
                       Kmat, Vmat, qmat, U_part, S_part);
    hipLaunchKernelGGL(slot_update_kernel, dim3(128), dim3(256), 0, stream,
                       U_part, S_part, slots, wcomb_b, wih_b, whh_b, w1_b, w2_b,
                       b_ih, b_hh, g_mlp, b_mlp, b1, b2,
                       wq_b, g_slot, b_slot, qmat,
                       outp, (it==2)?1:0, (it<2)?1:0);
  }
}

// Round 4
// 408.002 us; speedup vs baseline: 1.0106x; 1.0106x over previous
//
#include <hip/hip_runtime.h>

#define BB 32
#define NN 4096
#define DD 256
#define HH 4
#define KK 8
#define DH 64

typedef unsigned short u16;
typedef unsigned int u32;
typedef __attribute__((ext_vector_type(8))) short short8;
typedef __attribute__((ext_vector_type(4))) float f32x4;

__device__ __forceinline__ float b2f(u16 u){ return __uint_as_float(((u32)u)<<16); }
__device__ __forceinline__ u16 f2b(float f){
  u32 u = __float_as_uint(f);
  u32 r = (u + 0x7fffu + ((u>>16)&1u)) >> 16;  // RNE
  return (u16)r;
}

__device__ __forceinline__ float dot128(const u16* __restrict__ wr, const float* __restrict__ v){
  float a0=0,a1=0,a2=0,a3=0;
  #pragma unroll
  for (int d=0; d<128; d+=8){
    const short8 wv = *(const short8*)(wr+d);
    a0 = fmaf(b2f((u16)wv[0]), v[d+0], a0);
    a1 = fmaf(b2f((u16)wv[1]), v[d+1], a1);
    a2 = fmaf(b2f((u16)wv[2]), v[d+2], a2);
    a3 = fmaf(b2f((u16)wv[3]), v[d+3], a3);
    a0 = fmaf(b2f((u16)wv[4]), v[d+4], a0);
    a1 = fmaf(b2f((u16)wv[5]), v[d+5], a1);
    a2 = fmaf(b2f((u16)wv[6]), v[d+6], a2);
    a3 = fmaf(b2f((u16)wv[7]), v[d+7], a3);
  }
  return (a0+a1)+(a2+a3);
}

// ---------------- prep: convert weights to bf16 (wkv pre-swizzled), init slots ----------------
__global__ __launch_bounds__(256) void prep_kernel(
    const float* __restrict__ mu, const float* __restrict__ w_q,
    const float* __restrict__ w_k, const float* __restrict__ w_v,
    const float* __restrict__ w_comb, const float* __restrict__ w_ih,
    const float* __restrict__ w_hh, const float* __restrict__ w1,
    const float* __restrict__ w2,
    u16* __restrict__ wkv, u16* __restrict__ wq_b, u16* __restrict__ wcomb_b,
    u16* __restrict__ wih_b, u16* __restrict__ whh_b, u16* __restrict__ w1_b,
    u16* __restrict__ w2_b, float* __restrict__ slots)
{
  int i = blockIdx.x*256 + threadIdx.x;
  if (i < 131072) {
    int c = i>>8, d = i&255;
    float v = (c<256) ? w_k[c*256+d] : w_v[(c-256)*256+d];
    // pre-swizzle so linear LDS staging yields XOR-swizzled tile (involution)
    int off = (c<<9) + ((2*d) ^ ((c&15)<<4));
    wkv[off>>1] = f2b(v);
    return;
  }
  i -= 131072;
  if (i < 65536){ wq_b[i] = f2b(w_q[i]); return; } i -= 65536;
  if (i < 65536){ wcomb_b[i] = f2b(w_comb[i]); return; } i -= 65536;
  if (i < 196608){ wih_b[i] = f2b(w_ih[i]); return; } i -= 196608;
  if (i < 196608){ whh_b[i] = f2b(w_hh[i]); return; } i -= 196608;
  if (i < 65536){ w1_b[i] = f2b(w1[i]); return; } i -= 65536;
  if (i < 65536){ w2_b[i] = f2b(w2[i]); return; } i -= 65536;
  if (i < 65536){ slots[i] = mu[i & 2047]; return; }
}

// ---------------- phase A: fused LN(x) + K/V projection (MFMA bf16) ----------------
// R2 known-good: 64 rows x 512 cols per block, 8 waves, 72 KB LDS.
__global__ __launch_bounds__(512) void kv_proj_kernel(
    const float* __restrict__ x, const float* __restrict__ g_in,
    const float* __restrict__ b_in, const u16* __restrict__ wkv,
    u16* __restrict__ Kmat, u16* __restrict__ Vmat)
{
  __shared__ __align__(16) u16 Atile[64*256];   // 32 KB, swizzled [row][k]
  __shared__ __align__(16) u16 Btile[64*256];   // 32 KB, swizzled [col][k], one 64-col chunk
  __shared__ __align__(16) u16 Cbuf[64*64];     // 8 KB, swizzled C repack
  const int tid = threadIdx.x;
  const int w = tid>>6, l = tid&63;
  const long row0 = (long)blockIdx.x * 64;

  // issue chunk-0 weight loads early, hide under LN
  short8 breg[4];
  #pragma unroll
  for (int i=0;i<4;++i)
    breg[i] = *(const short8*)((const char*)wkv + (i*512 + tid)*16);

  const f32x4 gv = *(const f32x4*)(g_in + l*4);
  const f32x4 bv = *(const f32x4*)(b_in + l*4);

  #pragma unroll
  for (int rr=0; rr<8; ++rr) {
    const int r = w*8 + rr;
    const f32x4 xv = *(const f32x4*)(x + (row0+r)*DD + l*4);
    float s = xv.x+xv.y+xv.z+xv.w;
    float s2 = xv.x*xv.x+xv.y*xv.y+xv.z*xv.z+xv.w*xv.w;
    #pragma unroll
    for (int m=1;m<64;m<<=1){ s += __shfl_xor(s,m); s2 += __shfl_xor(s2,m); }
    const float mean = s * (1.f/256.f);
    const float rstd = rsqrtf(s2*(1.f/256.f) - mean*mean + 1e-5f);
    const u32 p0 = (u32)f2b((xv.x-mean)*rstd*gv.x + bv.x) | ((u32)f2b((xv.y-mean)*rstd*gv.y + bv.y)<<16);
    const u32 p1 = (u32)f2b((xv.z-mean)*rstd*gv.z + bv.z) | ((u32)f2b((xv.w-mean)*rstd*gv.w + bv.w)<<16);
    const unsigned long long pp = (unsigned long long)p0 | ((unsigned long long)p1<<32);
    *(unsigned long long*)((char*)Atile + r*512 + ((l*8) ^ ((r&15)<<4))) = pp;
  }
  // commit staged chunk 0
  #pragma unroll
  for (int i=0;i<4;++i)
    *(short8*)((char*)Btile + (i*512+tid)*16) = breg[i];
  __syncthreads();

  const int wm = w>>2, wn = w&3;
  const int lr = l&15;
  const int lk = (l>>4)*8;

  for (int ct=0; ct<8; ++ct) {
    short8 nreg[4];
    if (ct < 7) {
      #pragma unroll
      for (int i=0;i<4;++i)
        nreg[i] = *(const short8*)((const char*)wkv + (ct+1)*32768 + (i*512 + tid)*16);
    }

    f32x4 acc0 = (f32x4)0.f, acc1 = (f32x4)0.f;
    #pragma unroll
    for (int ks=0; ks<8; ++ks) {
      const int k2 = (ks*32 + lk)*2;
      short8 af0, af1, bfv;
      { const int r = wm*32 + lr;       af0 = *(const short8*)((const char*)Atile + r*512 + (k2 ^ ((r&15)<<4))); }
      { const int r = wm*32 + 16 + lr;  af1 = *(const short8*)((const char*)Atile + r*512 + (k2 ^ ((r&15)<<4))); }
      { const int c = wn*16 + lr;       bfv = *(const short8*)((const char*)Btile + c*512 + (k2 ^ ((c&15)<<4))); }
      acc0 = __builtin_amdgcn_mfma_f32_16x16x32_bf16(af0, bfv, acc0, 0,0,0);
      acc1 = __builtin_amdgcn_mfma_f32_16x16x32_bf16(af1, bfv, acc1, 0,0,0);
    }

    {
      const int c = wn*16 + lr;
      #pragma unroll
      for (int reg=0; reg<4; ++reg) {
        const int r0r = wm*32 + (l>>4)*4 + reg;
        const int r1r = r0r + 16;
        *(u16*)((char*)Cbuf + r0r*128 + ((2*c) ^ ((r0r&7)<<4))) = f2b(acc0[reg]);
        *(u16*)((char*)Cbuf + r1r*128 + ((2*c) ^ ((r1r&7)<<4))) = f2b(acc1[reg]);
      }
    }
    __syncthreads();

    if (ct < 7) {
      #pragma unroll
      for (int i=0;i<4;++i)
        *(short8*)((char*)Btile + (i*512+tid)*16) = nreg[i];
    }
    {
      const int r = tid>>3, cg = tid&7;
      const short8 vv = *(const short8*)((char*)Cbuf + r*128 + ((cg*16) ^ ((r&7)<<4)));
      u16* dst = (ct<4) ? Kmat : Vmat;
      *(short8*)(dst + (row0+r)*DD + (ct&3)*64 + cg*8) = vv;
    }
    __syncthreads();
  }
}

// ---------------- iter-1 only: q = split(LN(slots) @ w_q^T) ----------------
__global__ __launch_bounds__(256) void slot_q_kernel(
    const float* __restrict__ slots, const float* __restrict__ g_slot,
    const float* __restrict__ b_slot, const u16* __restrict__ wq_b,
    float* __restrict__ qmat)
{
  __shared__ float xn[256];
  __shared__ float red[8];
  const int r = blockIdx.x, t = threadIdx.x;
  const int w = t>>6, l = t&63;
  const float xv = slots[r*256 + t];
  float s = xv, s2 = xv*xv;
  #pragma unroll
  for (int m=1;m<64;m<<=1){ s += __shfl_xor(s,m); s2 += __shfl_xor(s2,m); }
  if (l==0){ red[w*2]=s; red[w*2+1]=s2; }
  __syncthreads();
  s = red[0]+red[2]+red[4]+red[6];
  s2 = red[1]+red[3]+red[5]+red[7];
  const float mean = s*(1.f/256.f);
  const float rstd = rsqrtf(s2*(1.f/256.f)-mean*mean + 1e-5f);
  xn[t] = (xv-mean)*rstd*g_slot[t] + b_slot[t];
  __syncthreads();
  const u16* wr = wq_b + t*256;
  float a0=0,a1=0,a2=0,a3=0;
  for (int d=0; d<256; d+=8) {
    const short8 wv = *(const short8*)(wr + d);
    a0 = fmaf(b2f((u16)wv[0]), xn[d+0], a0);
    a1 = fmaf(b2f((u16)wv[1]), xn[d+1], a1);
    a2 = fmaf(b2f((u16)wv[2]), xn[d+2], a2);
    a3 = fmaf(b2f((u16)wv[3]), xn[d+3], a3);
    a0 = fmaf(b2f((u16)wv[4]), xn[d+4], a0);
    a1 = fmaf(b2f((u16)wv[5]), xn[d+5], a1);
    a2 = fmaf(b2f((u16)wv[6]), xn[d+6], a2);
    a3 = fmaf(b2f((u16)wv[7]), xn[d+7], a3);
  }
  qmat[r*256 + t] = ((a0+a1)+(a2+a3));
}

// ---------------- per-iter: fused dots -> softmax(k) -> partial sums (8 parts) ----------------
__global__ __launch_bounds__(256) void attn_kernel(
    const u16* __restrict__ Kmat, const u16* __restrict__ Vmat,
    const float* __restrict__ qmat, float* __restrict__ U_part,
    float* __restrict__ S_part)
{
  __shared__ float U_lds[4][8][64];
  __shared__ float S_lds[4][8];
  const int bid = blockIdx.x;
  const int part = bid & 7, h = (bid>>3)&3, b = bid>>5;
  const int t = threadIdx.x, w = t>>6, l = t&63;
  const int ds = l&7, ng = l>>3;

  float qreg[8][8];
  #pragma unroll
  for (int k=0;k<8;++k) {
    const f32x4 qa = *(const f32x4*)(qmat + (b*8+k)*256 + h*64 + ds*8);
    const f32x4 qb = *(const f32x4*)(qmat + (b*8+k)*256 + h*64 + ds*8 + 4);
    qreg[k][0]=qa.x; qreg[k][1]=qa.y; qreg[k][2]=qa.z; qreg[k][3]=qa.w;
    qreg[k][4]=qb.x; qreg[k][5]=qb.y; qreg[k][6]=qb.z; qreg[k][7]=qb.w;
  }

  float accU[8][8];
  float sacc[8];
  #pragma unroll
  for (int k=0;k<8;++k){ sacc[k]=0.f;
    #pragma unroll
    for (int j=0;j<8;++j) accU[k][j]=0.f; }

  const long base = ((long)b*NN)*DD + h*64;
  const u16* Kp = Kmat + base + (long)(part*512 + w*8 + ng)*DD + ds*8;
  const u16* Vp = Vmat + base + (long)(part*512 + w*8 + ng)*DD + ds*8;

  short8 kc = *(const short8*)Kp;
  short8 vc = *(const short8*)Vp;
  for (int pass=0; pass<16; ++pass) {
    short8 kn, vn;
    if (pass < 15) {
      kn = *(const short8*)(Kp + (pass+1)*32*DD);
      vn = *(const short8*)(Vp + (pass+1)*32*DD);
    }
    float kd[8];
    #pragma unroll
    for (int j=0;j<8;++j) kd[j] = b2f((u16)kc[j]);
    float dots[8];
    #pragma unroll
    for (int k=0;k<8;++k) {
      float d0 = qreg[k][0]*kd[0] + qreg[k][1]*kd[1] + qreg[k][2]*kd[2] + qreg[k][3]*kd[3]
               + qreg[k][4]*kd[4] + qreg[k][5]*kd[5] + qreg[k][6]*kd[6] + qreg[k][7]*kd[7];
      d0 += __shfl_xor(d0,1); d0 += __shfl_xor(d0,2); d0 += __shfl_xor(d0,4);
      dots[k] = d0 * 0.125f;
    }
    float mx = dots[0];
    #pragma unroll
    for (int k=1;k<8;++k) mx = fmaxf(mx, dots[k]);
    float e[8]; float se = 0.f;
    #pragma unroll
    for (int k=0;k<8;++k){ e[k] = __expf(dots[k]-mx); se += e[k]; }
    const float inv = 1.f/se;
    float vd[8];
    #pragma unroll
    for (int j=0;j<8;++j) vd[j] = b2f((u16)vc[j]);
    #pragma unroll
    for (int k=0;k<8;++k) {
      const float p = e[k]*inv;
      sacc[k] += p;
      #pragma unroll
      for (int j=0;j<8;++j) accU[k][j] = fmaf(p, vd[j], accU[k][j]);
    }
    kc = kn; vc = vn;
  }
  #pragma unroll
  for (int k=0;k<8;++k){
    #pragma unroll
    for (int j=0;j<8;++j){
      float v = accU[k][j];
      v += __shfl_xor(v,8); v += __shfl_xor(v,16); v += __shfl_xor(v,32);
      accU[k][j]=v;
    }
    float sv = sacc[k];
    sv += __shfl_xor(sv,8); sv += __shfl_xor(sv,16); sv += __shfl_xor(sv,32);
    sacc[k]=sv;
  }
  if (l<8){
    #pragma unroll
    for (int k=0;k<8;++k)
      #pragma unroll
      for (int j=0;j<8;++j) U_lds[w][k][l*8+j] = accU[k][j];
  }
  if (l==0){
    #pragma unroll
    for (int k=0;k<8;++k) S_lds[w][k]=sacc[k];
  }
  __syncthreads();
  for (int i=t;i<512;i+=256){
    const int k=i>>6, d=i&63;
    U_part[(((long)part*32 + b)*4 + h)*512 + k*64 + d] =
      U_lds[0][k][d]+U_lds[1][k][d]+U_lds[2][k][d]+U_lds[3][k][d];
  }
  if (t<8){
    S_part[((part*32 + b)*4 + h)*8 + t] = S_lds[0][t]+S_lds[1][t]+S_lds[2][t]+S_lds[3][t];
  }
}

// ---------------- per-iter: renorm + comb + GRU + MLP (+ fused next-iter q) ----------------
// One slot row per block, 512 threads: col = t&255, kh = t>>8 (K-half split).
__global__ __launch_bounds__(512) void slot_update_kernel(
    const float* __restrict__ U_part, const float* __restrict__ S_part,
    float* __restrict__ slots,
    const u16* __restrict__ wcomb_b, const u16* __restrict__ wih_b,
    const u16* __restrict__ whh_b, const u16* __restrict__ w1_b,
    const u16* __restrict__ w2_b,
    const float* __restrict__ b_ih, const float* __restrict__ b_hh,
    const float* __restrict__ g_mlp, const float* __restrict__ b_mlp,
    const float* __restrict__ b1v, const float* __restrict__ b2v,
    const u16* __restrict__ wq_b, const float* __restrict__ g_slot,
    const float* __restrict__ b_slot, float* __restrict__ qmat,
    float* __restrict__ out_final, const int write_out, const int compute_q)
{
  __shared__ float hvec[256], uvec[256], cvec[256], xvec[256], nvec[256];
  __shared__ float part2[2][256];
  __shared__ float part6[6][2][256];
  __shared__ float red[8];
  const int r = blockIdx.x, t = threadIdx.x;
  const int col = t&255, kh = t>>8;
  const int w = t>>6, l = t&63;

  if (t < 256) {
    hvec[col] = slots[r*256 + col];
    const int b = r>>3, k = r&7, h = col>>6, d = col&63;
    float ssum=0.f, usum=0.f;
    #pragma unroll
    for (int p=0;p<8;++p){
      ssum += S_part[((p*32+b)*4+h)*8 + k];
      usum += U_part[(((long)p*32+b)*4+h)*512 + k*64 + d];
    }
    uvec[col] = usum/(ssum + 1e-8f);
  }
  __syncthreads();

  // comb = wcomb @ u
  part2[kh][col] = dot128(wcomb_b + col*256 + kh*128, &uvec[kh*128]);
  __syncthreads();
  if (t<256) cvec[col] = part2[0][col] + part2[1][col];
  __syncthreads();

  // GRU: 6 matvec halves
  part6[0][kh][col] = dot128(wih_b + (0*256+col)*256 + kh*128, &cvec[kh*128]);
  part6[1][kh][col] = dot128(wih_b + (1*256+col)*256 + kh*128, &cvec[kh*128]);
  part6[2][kh][col] = dot128(wih_b + (2*256+col)*256 + kh*128, &cvec[kh*128]);
  part6[3][kh][col] = dot128(whh_b + (0*256+col)*256 + kh*128, &hvec[kh*128]);
  part6[4][kh][col] = dot128(whh_b + (1*256+col)*256 + kh*128, &hvec[kh*128]);
  part6[5][kh][col] = dot128(whh_b + (2*256+col)*256 + kh*128, &hvec[kh*128]);
  __syncthreads();

  float newv = 0.f;
  if (t<256){
    const float ir = part6[0][0][col]+part6[0][1][col] + b_ih[col];
    const float iz = part6[1][0][col]+part6[1][1][col] + b_ih[256+col];
    const float inn= part6[2][0][col]+part6[2][1][col] + b_ih[512+col];
    const float hr = part6[3][0][col]+part6[3][1][col] + b_hh[col];
    const float hz = part6[4][0][col]+part6[4][1][col] + b_hh[256+col];
    const float hn = part6[5][0][col]+part6[5][1][col] + b_hh[512+col];
    const float rg = 1.f/(1.f + __expf(-(ir+hr)));
    const float zg = 1.f/(1.f + __expf(-(iz+hz)));
    float targ = inn + rg*hn;
    targ = fminf(fmaxf(targ, -15.f), 15.f);
    const float ex = __expf(2.f*targ);
    const float ng = (ex-1.f)/(ex+1.f);
    newv = (1.f-zg)*ng + zg*hvec[col];
    nvec[col] = newv;
    float s = newv, s2 = newv*newv;
    #pragma unroll
    for (int m=1;m<64;m<<=1){ s += __shfl_xor(s,m); s2 += __shfl_xor(s2,m); }
    if (l==0){ red[w*2]=s; red[w*2+1]=s2; }
  }
  __syncthreads();
  if (t<256){
    const float s  = red[0]+red[2]+red[4]+red[6];
    const float s2 = red[1]+red[3]+red[5]+red[7];
    const float mean = s*(1.f/256.f);
    const float rstd = rsqrtf(s2*(1.f/256.f)-mean*mean + 1e-5f);
    xvec[col] = (newv-mean)*rstd*g_mlp[col] + b_mlp[col];
  }
  __syncthreads();

  // hid = relu(w1 @ xn + b1)
  part2[kh][col] = dot128(w1_b + col*256 + kh*128, &xvec[kh*128]);
  __syncthreads();
  if (t<256) cvec[col] = fmaxf(part2[0][col]+part2[1][col] + b1v[col], 0.f);
  __syncthreads();

  // out = new + w2 @ hid + b2
  part2[kh][col] = dot128(w2_b + col*256 + kh*128, &cvec[kh*128]);
  __syncthreads();
  float o = 0.f;
  if (t<256){
    o = nvec[col] + part2[0][col]+part2[1][col] + b2v[col];
    slots[r*256 + col] = o;
    if (write_out) out_final[r*256 + col] = o;
    if (compute_q){
      float s = o, s2 = o*o;
      #pragma unroll
      for (int m=1;m<64;m<<=1){ s += __shfl_xor(s,m); s2 += __shfl_xor(s2,m); }
      if (l==0){ red[w*2]=s; red[w*2+1]=s2; }
    }
  }
  if (compute_q){
    __syncthreads();
    if (t<256){
      const float s  = red[0]+red[2]+red[4]+red[6];
      const float s2 = red[1]+red[3]+red[5]+red[7];
      const float mean = s*(1.f/256.f);
      const float rstd = rsqrtf(s2*(1.f/256.f)-mean*mean + 1e-5f);
      xvec[col] = (o-mean)*rstd*g_slot[col] + b_slot[col];
    }
    __syncthreads();
    part2[kh][col] = dot128(wq_b + col*256 + kh*128, &xvec[kh*128]);
    __syncthreads();
    if (t<256) qmat[r*256 + col] = part2[0][col] + part2[1][col];
  }
}

extern "C" void kernel_launch(void* const* d_in, const int* in_sizes, int n_in,
                              void* d_out, int out_size, void* d_ws, size_t ws_size,
                              hipStream_t stream)
{
  (void)in_sizes; (void)n_in; (void)out_size; (void)ws_size;
  const float* x      = (const float*)d_in[0];
  const float* mu     = (const float*)d_in[1];
  const float* w_q    = (const float*)d_in[2];
  const float* w_k    = (const float*)d_in[3];
  const float* w_v    = (const float*)d_in[4];
  const float* w_comb = (const float*)d_in[5];
  const float* g_in   = (const float*)d_in[6];
  const float* b_in   = (const float*)d_in[7];
  const float* g_slot = (const float*)d_in[8];
  const float* b_slot = (const float*)d_in[9];
  const float* g_mlp  = (const float*)d_in[10];
  const float* b_mlp  = (const float*)d_in[11];
  const float* w_ih   = (const float*)d_in[12];
  const float* w_hh   = (const float*)d_in[13];
  const float* b_ih   = (const float*)d_in[14];
  const float* b_hh   = (const float*)d_in[15];
  const float* w1     = (const float*)d_in[16];
  const float* b1     = (const float*)d_in[17];
  const float* w2     = (const float*)d_in[18];
  const float* b2     = (const float*)d_in[19];

  char* ws = (char*)d_ws;
  u16* Kmat    = (u16*)(ws + 0);
  u16* Vmat    = (u16*)(ws + 67108864);
  u16* wkv     = (u16*)(ws + 134217728);
  u16* wq_b    = (u16*)(ws + 134479872);
  u16* wcomb_b = (u16*)(ws + 134610944);
  u16* wih_b   = (u16*)(ws + 134742016);
  u16* whh_b   = (u16*)(ws + 135135232);
  u16* w1_b    = (u16*)(ws + 135528448);
  u16* w2_b    = (u16*)(ws + 135659520);
  float* slots = (float*)(ws + 135790592);
  float* qmat  = (float*)(ws + 136052736);
  float* U_part= (float*)(ws + 136314880);   // 8*32*4*512*4 = 2 MB
  float* S_part= (float*)(ws + 138412032);   // 32 KB

  hipLaunchKernelGGL(prep_kernel, dim3(3328), dim3(256), 0, stream,
                     mu, w_q, w_k, w_v, w_comb, w_ih, w_hh, w1, w2,
                     wkv, wq_b, wcomb_b, wih_b, whh_b, w1_b, w2_b, slots);
  hipLaunchKernelGGL(kv_proj_kernel, dim3(2048), dim3(512), 0, stream,
                     x, g_in, b_in, wkv, Kmat, Vmat);
  hipLaunchKernelGGL(slot_q_kernel, dim3(256), dim3(256), 0, stream,
                     slots, g_slot, b_slot, wq_b, qmat);
  float* outp = (float*)d_out;
  for (int it=0; it<3; ++it) {
    hipLaunchKernelGGL(attn_kernel, dim3(1024), dim3(256), 0, stream,
                       Kmat, Vmat, qmat, U_part, S_part);
    hipLaunchKernelGGL(slot_update_kernel, dim3(256), dim3(512), 0, stream,
                       U_part, S_part, slots, wcomb_b, wih_b, whh_b, w1_b, w2_b,
                       b_ih, b_hh, g_mlp, b_mlp, b1, b2,
                       wq_b, g_slot, b_slot, qmat,
                       outp, (it==2)?1:0, (it<2)?1:0);
  }
}

// Round 5
// 350.183 us; speedup vs baseline: 1.1774x; 1.1651x over previous
//
#include <hip/hip_runtime.h>

#define BB 32
#define NN 4096
#define DD 256
#define HH 4
#define KK 8
#define DH 64

typedef unsigned short u16;
typedef unsigned int u32;
typedef __attribute__((ext_vector_type(8))) short short8;
typedef __attribute__((ext_vector_type(4))) float f32x4;

__device__ __forceinline__ float b2f(u16 u){ return __uint_as_float(((u32)u)<<16); }
__device__ __forceinline__ u16 f2b(float f){
  u32 u = __float_as_uint(f);
  u32 r = (u + 0x7fffu + ((u>>16)&1u)) >> 16;  // RNE
  return (u16)r;
}

// ---------------- prep: convert weights to bf16 (wkv pre-swizzled), init slots ----------------
__global__ __launch_bounds__(256) void prep_kernel(
    const float* __restrict__ mu, const float* __restrict__ w_q,
    const float* __restrict__ w_k, const float* __restrict__ w_v,
    const float* __restrict__ w_comb, const float* __restrict__ w_ih,
    const float* __restrict__ w_hh, const float* __restrict__ w1,
    const float* __restrict__ w2,
    u16* __restrict__ wkv, u16* __restrict__ wq_b, u16* __restrict__ wcomb_b,
    u16* __restrict__ wih_b, u16* __restrict__ whh_b, u16* __restrict__ w1_b,
    u16* __restrict__ w2_b, float* __restrict__ slots)
{
  int i = blockIdx.x*256 + threadIdx.x;
  if (i < 131072) {
    int c = i>>8, d = i&255;
    float v = (c<256) ? w_k[c*256+d] : w_v[(c-256)*256+d];
    // pre-swizzle so linear LDS staging yields XOR-swizzled tile (involution)
    int off = (c<<9) + ((2*d) ^ ((c&15)<<4));
    wkv[off>>1] = f2b(v);
    return;
  }
  i -= 131072;
  if (i < 65536){ wq_b[i] = f2b(w_q[i]); return; } i -= 65536;
  if (i < 65536){ wcomb_b[i] = f2b(w_comb[i]); return; } i -= 65536;
  if (i < 196608){ wih_b[i] = f2b(w_ih[i]); return; } i -= 196608;
  if (i < 196608){ whh_b[i] = f2b(w_hh[i]); return; } i -= 196608;
  if (i < 65536){ w1_b[i] = f2b(w1[i]); return; } i -= 65536;
  if (i < 65536){ w2_b[i] = f2b(w2[i]); return; } i -= 65536;
  if (i < 65536){ slots[i] = mu[i & 2047]; return; }
}

// ---------------- phase A: fused LN(x) + K/V projection (MFMA bf16) ----------------
// R2 structure + A-fragments register-resident (read Atile once, not per chunk).
__global__ __launch_bounds__(512,4) void kv_proj_kernel(
    const float* __restrict__ x, const float* __restrict__ g_in,
    const float* __restrict__ b_in, const u16* __restrict__ wkv,
    u16* __restrict__ Kmat, u16* __restrict__ Vmat)
{
  __shared__ __align__(16) u16 Atile[64*256];   // 32 KB, swizzled [row][k]
  __shared__ __align__(16) u16 Btile[64*256];   // 32 KB, swizzled [col][k], one 64-col chunk
  __shared__ __align__(16) u16 Cbuf[64*64];     // 8 KB, swizzled C repack
  const int tid = threadIdx.x;
  const int w = tid>>6, l = tid&63;
  const long row0 = (long)blockIdx.x * 64;

  // issue chunk-0 weight loads early, hide under LN
  short8 breg[4];
  #pragma unroll
  for (int i=0;i<4;++i)
    breg[i] = *(const short8*)((const char*)wkv + (i*512 + tid)*16);

  const f32x4 gv = *(const f32x4*)(g_in + l*4);
  const f32x4 bv = *(const f32x4*)(b_in + l*4);

  #pragma unroll
  for (int rr=0; rr<8; ++rr) {
    const int r = w*8 + rr;
    const f32x4 xv = *(const f32x4*)(x + (row0+r)*DD + l*4);
    float s = xv.x+xv.y+xv.z+xv.w;
    float s2 = xv.x*xv.x+xv.y*xv.y+xv.z*xv.z+xv.w*xv.w;
    #pragma unroll
    for (int m=1;m<64;m<<=1){ s += __shfl_xor(s,m); s2 += __shfl_xor(s2,m); }
    const float mean = s * (1.f/256.f);
    const float rstd = rsqrtf(s2*(1.f/256.f) - mean*mean + 1e-5f);
    const u32 p0 = (u32)f2b((xv.x-mean)*rstd*gv.x + bv.x) | ((u32)f2b((xv.y-mean)*rstd*gv.y + bv.y)<<16);
    const u32 p1 = (u32)f2b((xv.z-mean)*rstd*gv.z + bv.z) | ((u32)f2b((xv.w-mean)*rstd*gv.w + bv.w)<<16);
    const unsigned long long pp = (unsigned long long)p0 | ((unsigned long long)p1<<32);
    *(unsigned long long*)((char*)Atile + r*512 + ((l*8) ^ ((r&15)<<4))) = pp;
  }
  // commit staged chunk 0
  #pragma unroll
  for (int i=0;i<4;++i)
    *(short8*)((char*)Btile + (i*512+tid)*16) = breg[i];
  __syncthreads();

  const int wm = w>>2, wn = w&3;
  const int lr = l&15;
  const int lk = (l>>4)*8;

  // A-fragments register-resident: read Atile ONCE (not once per chunk)
  short8 afr0[8], afr1[8];
  #pragma unroll
  for (int ks=0; ks<8; ++ks) {
    const int k2 = (ks*32 + lk)*2;
    const int r0r = wm*32 + lr;
    const int r1r = wm*32 + 16 + lr;
    afr0[ks] = *(const short8*)((const char*)Atile + r0r*512 + (k2 ^ ((r0r&15)<<4)));
    afr1[ks] = *(const short8*)((const char*)Atile + r1r*512 + (k2 ^ ((r1r&15)<<4)));
  }
  // opacity: prevent rematerialization of the LDS reads (keep frags in VGPRs)
  #pragma unroll
  for (int ks=0; ks<8; ++ks) {
    asm volatile("" : "+v"(afr0[ks]));
    asm volatile("" : "+v"(afr1[ks]));
  }

  for (int ct=0; ct<8; ++ct) {   // rolled loop (unroll was R3's remat trigger)
    short8 nreg[4];
    if (ct < 7) {
      #pragma unroll
      for (int i=0;i<4;++i)
        nreg[i] = *(const short8*)((const char*)wkv + (ct+1)*32768 + (i*512 + tid)*16);
    }

    f32x4 acc0 = (f32x4)0.f, acc1 = (f32x4)0.f;
    #pragma unroll
    for (int ks=0; ks<8; ++ks) {
      const int k2 = (ks*32 + lk)*2;
      const int c = wn*16 + lr;
      const short8 bfv = *(const short8*)((const char*)Btile + c*512 + (k2 ^ ((c&15)<<4)));
      acc0 = __builtin_amdgcn_mfma_f32_16x16x32_bf16(afr0[ks], bfv, acc0, 0,0,0);
      acc1 = __builtin_amdgcn_mfma_f32_16x16x32_bf16(afr1[ks], bfv, acc1, 0,0,0);
    }

    {
      const int c = wn*16 + lr;
      #pragma unroll
      for (int reg=0; reg<4; ++reg) {
        const int r0r = wm*32 + (l>>4)*4 + reg;
        const int r1r = r0r + 16;
        *(u16*)((char*)Cbuf + r0r*128 + ((2*c) ^ ((r0r&7)<<4))) = f2b(acc0[reg]);
        *(u16*)((char*)Cbuf + r1r*128 + ((2*c) ^ ((r1r&7)<<4))) = f2b(acc1[reg]);
      }
    }
    __syncthreads();

    if (ct < 7) {
      #pragma unroll
      for (int i=0;i<4;++i)
        *(short8*)((char*)Btile + (i*512+tid)*16) = nreg[i];
    }
    {
      const int r = tid>>3, cg = tid&7;
      const short8 vv = *(const short8*)((char*)Cbuf + r*128 + ((cg*16) ^ ((r&7)<<4)));
      u16* dst = (ct<4) ? Kmat : Vmat;
      *(short8*)(dst + (row0+r)*DD + (ct&3)*64 + cg*8) = vv;
    }
    __syncthreads();
  }
}

// ---------------- iter-1 only: q = split(LN(slots) @ w_q^T) ----------------
__global__ __launch_bounds__(256) void slot_q_kernel(
    const float* __restrict__ slots, const float* __restrict__ g_slot,
    const float* __restrict__ b_slot, const u16* __restrict__ wq_b,
    float* __restrict__ qmat)
{
  __shared__ float xn[256];
  __shared__ float red[8];
  const int r = blockIdx.x, t = threadIdx.x;
  const int w = t>>6, l = t&63;
  const float xv = slots[r*256 + t];
  float s = xv, s2 = xv*xv;
  #pragma unroll
  for (int m=1;m<64;m<<=1){ s += __shfl_xor(s,m); s2 += __shfl_xor(s2,m); }
  if (l==0){ red[w*2]=s; red[w*2+1]=s2; }
  __syncthreads();
  s = red[0]+red[2]+red[4]+red[6];
  s2 = red[1]+red[3]+red[5]+red[7];
  const float mean = s*(1.f/256.f);
  const float rstd = rsqrtf(s2*(1.f/256.f)-mean*mean + 1e-5f);
  xn[t] = (xv-mean)*rstd*g_slot[t] + b_slot[t];
  __syncthreads();
  const u16* wr = wq_b + t*256;
  float a0=0,a1=0,a2=0,a3=0;
  for (int d=0; d<256; d+=8) {
    const short8 wv = *(const short8*)(wr + d);
    a0 = fmaf(b2f((u16)wv[0]), xn[d+0], a0);
    a1 = fmaf(b2f((u16)wv[1]), xn[d+1], a1);
    a2 = fmaf(b2f((u16)wv[2]), xn[d+2], a2);
    a3 = fmaf(b2f((u16)wv[3]), xn[d+3], a3);
    a0 = fmaf(b2f((u16)wv[4]), xn[d+4], a0);
    a1 = fmaf(b2f((u16)wv[5]), xn[d+5], a1);
    a2 = fmaf(b2f((u16)wv[6]), xn[d+6], a2);
    a3 = fmaf(b2f((u16)wv[7]), xn[d+7], a3);
  }
  qmat[r*256 + t] = ((a0+a1)+(a2+a3));
}

// ---------------- per-iter: fused dots -> softmax(k) -> partial sums (4 parts) ----------------
__global__ __launch_bounds__(256) void attn_kernel(
    const u16* __restrict__ Kmat, const u16* __restrict__ Vmat,
    const float* __restrict__ qmat, float* __restrict__ U_part,
    float* __restrict__ S_part)
{
  __shared__ float U_lds[4][8][64];
  __shared__ float S_lds[4][8];
  const int bid = blockIdx.x;
  const int part = bid & 3, h = (bid>>2)&3, b = bid>>4;
  const int t = threadIdx.x, w = t>>6, l = t&63;
  const int ds = l&7, ng = l>>3;   // 8 lanes per n; ds = d-slice

  float qreg[8][8];
  #pragma unroll
  for (int k=0;k<8;++k) {
    const f32x4 qa = *(const f32x4*)(qmat + (b*8+k)*256 + h*64 + ds*8);
    const f32x4 qb = *(const f32x4*)(qmat + (b*8+k)*256 + h*64 + ds*8 + 4);
    qreg[k][0]=qa.x; qreg[k][1]=qa.y; qreg[k][2]=qa.z; qreg[k][3]=qa.w;
    qreg[k][4]=qb.x; qreg[k][5]=qb.y; qreg[k][6]=qb.z; qreg[k][7]=qb.w;
  }

  float accU[8][8];
  float sacc[8];
  #pragma unroll
  for (int k=0;k<8;++k){ sacc[k]=0.f;
    #pragma unroll
    for (int j=0;j<8;++j) accU[k][j]=0.f; }

  const long base = ((long)b*NN)*DD + h*64;
  const u16* Kp = Kmat + base + (long)(part*1024 + w*8 + ng)*DD + ds*8;
  const u16* Vp = Vmat + base + (long)(part*1024 + w*8 + ng)*DD + ds*8;

  short8 kc = *(const short8*)Kp;
  short8 vc = *(const short8*)Vp;
  for (int pass=0; pass<32; ++pass) {
    short8 kn, vn;
    if (pass < 31) {                 // prefetch next pass's K AND V
      kn = *(const short8*)(Kp + (pass+1)*32*DD);
      vn = *(const short8*)(Vp + (pass+1)*32*DD);
    }
    float kd[8];
    #pragma unroll
    for (int j=0;j<8;++j) kd[j] = b2f((u16)kc[j]);
    float dots[8];
    #pragma unroll
    for (int k=0;k<8;++k) {
      float d0 = qreg[k][0]*kd[0] + qreg[k][1]*kd[1] + qreg[k][2]*kd[2] + qreg[k][3]*kd[3]
               + qreg[k][4]*kd[4] + qreg[k][5]*kd[5] + qreg[k][6]*kd[6] + qreg[k][7]*kd[7];
      d0 += __shfl_xor(d0,1); d0 += __shfl_xor(d0,2); d0 += __shfl_xor(d0,4);
      dots[k] = d0 * 0.125f;   // SCALE = d_h^-0.5
    }
    float mx = dots[0];
    #pragma unroll
    for (int k=1;k<8;++k) mx = fmaxf(mx, dots[k]);
    float e[8]; float se = 0.f;
    #pragma unroll
    for (int k=0;k<8;++k){ e[k] = __expf(dots[k]-mx); se += e[k]; }
    const float inv = 1.f/se;
    float vd[8];
    #pragma unroll
    for (int j=0;j<8;++j) vd[j] = b2f((u16)vc[j]);
    #pragma unroll
    for (int k=0;k<8;++k) {
      const float p = e[k]*inv;
      sacc[k] += p;
      #pragma unroll
      for (int j=0;j<8;++j) accU[k][j] = fmaf(p, vd[j], accU[k][j]);
    }
    kc = kn; vc = vn;
  }
  #pragma unroll
  for (int k=0;k<8;++k){
    #pragma unroll
    for (int j=0;j<8;++j){
      float v = accU[k][j];
      v += __shfl_xor(v,8); v += __shfl_xor(v,16); v += __shfl_xor(v,32);
      accU[k][j]=v;
    }
    float sv = sacc[k];
    sv += __shfl_xor(sv,8); sv += __shfl_xor(sv,16); sv += __shfl_xor(sv,32);
    sacc[k]=sv;
  }
  if (l<8){
    #pragma unroll
    for (int k=0;k<8;++k)
      #pragma unroll
      for (int j=0;j<8;++j) U_lds[w][k][l*8+j] = accU[k][j];
  }
  if (l==0){
    #pragma unroll
    for (int k=0;k<8;++k) S_lds[w][k]=sacc[k];
  }
  __syncthreads();
  for (int i=t;i<512;i+=256){
    const int k=i>>6, d=i&63;
    U_part[(((long)part*32 + b)*4 + h)*512 + k*64 + d] =
      U_lds[0][k][d]+U_lds[1][k][d]+U_lds[2][k][d]+U_lds[3][k][d];
  }
  if (t<8){
    S_part[((part*32 + b)*4 + h)*8 + t] = S_lds[0][t]+S_lds[1][t]+S_lds[2][t]+S_lds[3][t];
  }
}

// ---------------- per-iter: renorm + comb + GRU + MLP (+ fused next-iter q) ----------------
__global__ __launch_bounds__(256) void slot_update_kernel(
    const float* __restrict__ U_part, const float* __restrict__ S_part,
    float* __restrict__ slots,
    const u16* __restrict__ wcomb_b, const u16* __restrict__ wih_b,
    const u16* __restrict__ whh_b, const u16* __restrict__ w1_b,
    const u16* __restrict__ w2_b,
    const float* __restrict__ b_ih, const float* __restrict__ b_hh,
    const float* __restrict__ g_mlp, const float* __restrict__ b_mlp,
    const float* __restrict__ b1v, const float* __restrict__ b2v,
    const u16* __restrict__ wq_b, const float* __restrict__ g_slot,
    const float* __restrict__ b_slot, float* __restrict__ qmat,
    float* __restrict__ out_final, const int write_out, const int compute_q)
{
  __shared__ float uL[2][256];
  __shared__ float hL[2][256];
  __shared__ float cL[2][256];
  __shared__ float xL[2][256];
  __shared__ float red[16];
  const int blk = blockIdx.x, t = threadIdx.x;
  const int w = t>>6, l = t&63;
  const int r0 = blk*2;

  #pragma unroll
  for (int rr=0;rr<2;++rr) hL[rr][t] = slots[(r0+rr)*256 + t];

  #pragma unroll
  for (int rr=0;rr<2;++rr) {
    const int r = r0+rr, b = r>>3, k = r&7;
    const int h = t>>6, d = t&63;
    float ssum = 0.f, usum = 0.f;
    #pragma unroll
    for (int p=0;p<4;++p) {
      ssum += S_part[((p*32 + b)*4 + h)*8 + k];
      usum += U_part[(((long)p*32 + b)*4 + h)*512 + k*64 + d];
    }
    uL[rr][t] = usum / (ssum + 1e-8f);
  }
  __syncthreads();

  {  // comb = upd @ w_comb^T
    float c00=0,c01=0,c10=0,c11=0;
    const u16* wr = wcomb_b + t*256;
    for (int d0=0; d0<256; d0+=8) {
      const short8 wv = *(const short8*)(wr + d0);
      float wf[8];
      #pragma unroll
      for (int j=0;j<8;++j) wf[j]=b2f((u16)wv[j]);
      #pragma unroll
      for (int j=0;j<8;j+=2) {
        c00 = fmaf(wf[j],   uL[0][d0+j],   c00);
        c01 = fmaf(wf[j+1], uL[0][d0+j+1], c01);
        c10 = fmaf(wf[j],   uL[1][d0+j],   c10);
        c11 = fmaf(wf[j+1], uL[1][d0+j+1], c11);
      }
    }
    cL[0][t]=c00+c01; cL[1][t]=c10+c11;
  }
  __syncthreads();

  // GRU gates: gi from cL (u), gh from hL (h)
  float gi[3][2], gh[3][2];
  #pragma unroll
  for (int g=0; g<3; ++g){ gi[g][0]=0; gi[g][1]=0; gh[g][0]=0; gh[g][1]=0; }
  for (int d0=0; d0<256; d0+=8) {
    float u0[8],u1[8],h0[8],h1[8];
    #pragma unroll
    for (int j=0;j<8;j+=4) {
      *(f32x4*)&u0[j] = *(const f32x4*)&cL[0][d0+j];
      *(f32x4*)&u1[j] = *(const f32x4*)&cL[1][d0+j];
      *(f32x4*)&h0[j] = *(const f32x4*)&hL[0][d0+j];
      *(f32x4*)&h1[j] = *(const f32x4*)&hL[1][d0+j];
    }
    #pragma unroll
    for (int g=0; g<3; ++g) {
      const short8 wi = *(const short8*)(wih_b + (g*256+t)*256 + d0);
      const short8 wh = *(const short8*)(whh_b + (g*256+t)*256 + d0);
      #pragma unroll
      for (int j=0;j<8;++j) {
        const float a = b2f((u16)wi[j]);
        const float bw = b2f((u16)wh[j]);
        gi[g][0] = fmaf(a, u0[j], gi[g][0]);
        gi[g][1] = fmaf(a, u1[j], gi[g][1]);
        gh[g][0] = fmaf(bw, h0[j], gh[g][0]);
        gh[g][1] = fmaf(bw, h1[j], gh[g][1]);
      }
    }
  }
  float newv[2];
  #pragma unroll
  for (int rr=0;rr<2;++rr) {
    const float ir = gi[0][rr] + b_ih[t];
    const float iz = gi[1][rr] + b_ih[256+t];
    const float inn= gi[2][rr] + b_ih[512+t];
    const float hr = gh[0][rr] + b_hh[t];
    const float hz = gh[1][rr] + b_hh[256+t];
    const float hn = gh[2][rr] + b_hh[512+t];
    const float rg = 1.f/(1.f + __expf(-(ir+hr)));
    const float zg = 1.f/(1.f + __expf(-(iz+hz)));
    float targ = inn + rg*hn;
    targ = fminf(fmaxf(targ, -15.f), 15.f);
    const float ex = __expf(2.f*targ);
    const float ng = (ex-1.f)/(ex+1.f);
    newv[rr] = (1.f-zg)*ng + zg*hL[rr][t];
  }

  // LN(new) with g_mlp/b_mlp
  float s0=newv[0], q0=newv[0]*newv[0], s1=newv[1], q1=newv[1]*newv[1];
  #pragma unroll
  for (int m=1;m<64;m<<=1){
    s0+=__shfl_xor(s0,m); q0+=__shfl_xor(q0,m);
    s1+=__shfl_xor(s1,m); q1+=__shfl_xor(q1,m);
  }
  if (l==0){ red[w*4]=s0; red[w*4+1]=q0; red[w*4+2]=s1; red[w*4+3]=q1; }
  __syncthreads();
  s0 = red[0]+red[4]+red[8]+red[12];
  q0 = red[1]+red[5]+red[9]+red[13];
  s1 = red[2]+red[6]+red[10]+red[14];
  q1 = red[3]+red[7]+red[11]+red[15];
  {
    const float m0 = s0*(1.f/256.f), m1 = s1*(1.f/256.f);
    const float r0v = rsqrtf(q0*(1.f/256.f)-m0*m0 + 1e-5f);
    const float r1v = rsqrtf(q1*(1.f/256.f)-m1*m1 + 1e-5f);
    xL[0][t] = (newv[0]-m0)*r0v*g_mlp[t] + b_mlp[t];
    xL[1][t] = (newv[1]-m1)*r1v*g_mlp[t] + b_mlp[t];
  }
  __syncthreads();

  {  // hid = relu(xn2 @ w1^T + b1) -> uL (reuse)
    float c00=0,c01=0,c10=0,c11=0;
    const u16* wr = w1_b + t*256;
    for (int d0=0; d0<256; d0+=8) {
      const short8 wv = *(const short8*)(wr + d0);
      float wf[8];
      #pragma unroll
      for (int j=0;j<8;++j) wf[j]=b2f((u16)wv[j]);
      #pragma unroll
      for (int j=0;j<8;j+=2) {
        c00 = fmaf(wf[j],   xL[0][d0+j],   c00);
        c01 = fmaf(wf[j+1], xL[0][d0+j+1], c01);
        c10 = fmaf(wf[j],   xL[1][d0+j],   c10);
        c11 = fmaf(wf[j+1], xL[1][d0+j+1], c11);
      }
    }
    uL[0][t] = fmaxf(c00+c01 + b1v[t], 0.f);
    uL[1][t] = fmaxf(c10+c11 + b1v[t], 0.f);
  }
  __syncthreads();

  float o0, o1;
  {  // out = new + hid @ w2^T + b2
    float c00=0,c01=0,c10=0,c11=0;
    const u16* wr = w2_b + t*256;
    for (int d0=0; d0<256; d0+=8) {
      const short8 wv = *(const short8*)(wr + d0);
      float wf[8];
      #pragma unroll
      for (int j=0;j<8;++j) wf[j]=b2f((u16)wv[j]);
      #pragma unroll
      for (int j=0;j<8;j+=2) {
        c00 = fmaf(wf[j],   uL[0][d0+j],   c00);
        c01 = fmaf(wf[j+1], uL[0][d0+j+1], c01);
        c10 = fmaf(wf[j],   uL[1][d0+j],   c10);
        c11 = fmaf(wf[j+1], uL[1][d0+j+1], c11);
      }
    }
    o0 = newv[0] + c00+c01 + b2v[t];
    o1 = newv[1] + c10+c11 + b2v[t];
    slots[(r0+0)*256 + t] = o0;
    slots[(r0+1)*256 + t] = o1;
    if (write_out){
      out_final[(r0+0)*256 + t] = o0;
      out_final[(r0+1)*256 + t] = o1;
    }
  }

  if (compute_q) {   // fused next-iteration q = split(LN(out) @ w_q^T)
    __syncthreads();
    float t0=o0, p0=o0*o0, t1=o1, p1=o1*o1;
    #pragma unroll
    for (int m=1;m<64;m<<=1){
      t0+=__shfl_xor(t0,m); p0+=__shfl_xor(p0,m);
      t1+=__shfl_xor(t1,m); p1+=__shfl_xor(p1,m);
    }
    if (l==0){ red[w*4]=t0; red[w*4+1]=p0; red[w*4+2]=t1; red[w*4+3]=p1; }
    __syncthreads();
    t0 = red[0]+red[4]+red[8]+red[12];
    p0 = red[1]+red[5]+red[9]+red[13];
    t1 = red[2]+red[6]+red[10]+red[14];
    p1 = red[3]+red[7]+red[11]+red[15];
    const float m0 = t0*(1.f/256.f), m1 = t1*(1.f/256.f);
    const float r0v = rsqrtf(p0*(1.f/256.f)-m0*m0 + 1e-5f);
    const float r1v = rsqrtf(p1*(1.f/256.f)-m1*m1 + 1e-5f);
    cL[0][t] = (o0-m0)*r0v*g_slot[t] + b_slot[t];
    cL[1][t] = (o1-m1)*r1v*g_slot[t] + b_slot[t];
    __syncthreads();
    float c00=0,c01=0,c10=0,c11=0;
    const u16* wr = wq_b + t*256;
    for (int d0=0; d0<256; d0+=8) {
      const short8 wv = *(const short8*)(wr + d0);
      float wf[8];
      #pragma unroll
      for (int j=0;j<8;++j) wf[j]=b2f((u16)wv[j]);
      #pragma unroll
      for (int j=0;j<8;j+=2) {
        c00 = fmaf(wf[j],   cL[0][d0+j],   c00);
        c01 = fmaf(wf[j+1], cL[0][d0+j+1], c01);
        c10 = fmaf(wf[j],   cL[1][d0+j],   c10);
        c11 = fmaf(wf[j+1], cL[1][d0+j+1], c11);
      }
    }
    qmat[(r0+0)*256 + t] = c00+c01;
    qmat[(r0+1)*256 + t] = c10+c11;
  }
}

extern "C" void kernel_launch(void* const* d_in, const int* in_sizes, int n_in,
                              void* d_out, int out_size, void* d_ws, size_t ws_size,
                              hipStream_t stream)
{
  (void)in_sizes; (void)n_in; (void)out_size; (void)ws_size;
  const float* x      = (const float*)d_in[0];
  const float* mu     = (const float*)d_in[1];
  const float* w_q    = (const float*)d_in[2];
  const float* w_k    = (const float*)d_in[3];
  const float* w_v    = (const float*)d_in[4];
  const float* w_comb = (const float*)d_in[5];
  const float* g_in   = (const float*)d_in[6];
  const float* b_in   = (const float*)d_in[7];
  const float* g_slot = (const float*)d_in[8];
  const float* b_slot = (const float*)d_in[9];
  const float* g_mlp  = (const float*)d_in[10];
  const float* b_mlp  = (const float*)d_in[11];
  const float* w_ih   = (const float*)d_in[12];
  const float* w_hh   = (const float*)d_in[13];
  const float* b_ih   = (const float*)d_in[14];
  const float* b_hh   = (const float*)d_in[15];
  const float* w1     = (const float*)d_in[16];
  const float* b1     = (const float*)d_in[17];
  const float* w2     = (const float*)d_in[18];
  const float* b2     = (const float*)d_in[19];

  char* ws = (char*)d_ws;
  u16* Kmat    = (u16*)(ws + 0);
  u16* Vmat    = (u16*)(ws + 67108864);
  u16* wkv     = (u16*)(ws + 134217728);
  u16* wq_b    = (u16*)(ws + 134479872);
  u16* wcomb_b = (u16*)(ws + 134610944);
  u16* wih_b   = (u16*)(ws + 134742016);
  u16* whh_b   = (u16*)(ws + 135135232);
  u16* w1_b    = (u16*)(ws + 135528448);
  u16* w2_b    = (u16*)(ws + 135659520);
  float* slots = (float*)(ws + 135790592);
  float* qmat  = (float*)(ws + 136052736);
  float* U_part= (float*)(ws + 136314880);
  float* S_part= (float*)(ws + 137363456);

  hipLaunchKernelGGL(prep_kernel, dim3(3328), dim3(256), 0, stream,
                     mu, w_q, w_k, w_v, w_comb, w_ih, w_hh, w1, w2,
                     wkv, wq_b, wcomb_b, wih_b, whh_b, w1_b, w2_b, slots);
  hipLaunchKernelGGL(kv_proj_kernel, dim3(2048), dim3(512), 0, stream,
                     x, g_in, b_in, wkv, Kmat, Vmat);
  hipLaunchKernelGGL(slot_q_kernel, dim3(256), dim3(256), 0, stream,
                     slots, g_slot, b_slot, wq_b, qmat);
  float* outp = (float*)d_out;
  for (int it=0; it<3; ++it) {
    hipLaunchKernelGGL(attn_kernel, dim3(512), dim3(256), 0, stream,
                       Kmat, Vmat, qmat, U_part, S_part);
    hipLaunchKernelGGL(slot_update_kernel, dim3(128), dim3(256), 0, stream,
                       U_part, S_part, slots, wcomb_b, wih_b, whh_b, w1_b, w2_b,
                       b_ih, b_hh, g_mlp, b_mlp, b1, b2,
                       wq_b, g_slot, b_slot, qmat,
                       outp, (it==2)?1:0, (it<2)?1:0);
  }
}